// Round 3
// baseline (149.991 us; speedup 1.0000x reference)
//
#include <hip/hip_runtime.h>
#include <math.h>

// Causal flash attention, B=2 H=16 S=2048 D=64, fp32 in/out, bf16 MFMA compute.
// R8: in-block K-split replaces cross-block z-split. 1024 blocks of 64 q
// (qb=0..31 per bh, LPT: biggest first), 4 waves = (q-set g, key-parity kpar).
// Each wave: one 32x32 unit per 64-key tile (4 QK + 4 PV MFMA). Partial O/l
// summed across kpar waves in LDS at block end; final fp32 O written directly.
// Combine kernel + partial-O buffers DELETED. launch_bounds(256,3) -> 3
// blocks/CU (3 waves/SIMD) for latency hiding.
// Carried: R7 VALU l-sum (no ones-MFMA), permlane32_swap P-exchange, zero-C
// vector, setprio(1) on MFMA clusters; R6 LDS XOR-swizzle staging via
// pre-swizzled global src + global_load_lds(16B), Q pre-scaled bf16 prepass,
// P pack via v_perm.

constexpr int kS   = 2048;
constexpr int kD   = 64;
constexpr int kBH  = 32;
constexpr int kPadP = 72;   // prep-kernel LDS pad only

typedef short short8 __attribute__((ext_vector_type(8)));
typedef float float4v __attribute__((ext_vector_type(4)));
typedef float float16v __attribute__((ext_vector_type(16)));
typedef unsigned int u32;
typedef unsigned short u16;

static __device__ inline u16 f2bf(float f) {
  union { float f; unsigned u; } v; v.f = f;
  unsigned r = v.u + 0x7FFF + ((v.u >> 16) & 1);   // RNE
  return (u16)(r >> 16);
}

static __device__ inline short8 pack8(float4v a, float4v b) {
  short8 r;
  r[0] = (short)f2bf(a[0]); r[1] = (short)f2bf(a[1]);
  r[2] = (short)f2bf(a[2]); r[3] = (short)f2bf(a[3]);
  r[4] = (short)f2bf(b[0]); r[5] = (short)f2bf(b[1]);
  r[6] = (short)f2bf(b[2]); r[7] = (short)f2bf(b[3]);
  return r;
}

static __device__ inline void async_cp16(const void* g, void* l) {
  __builtin_amdgcn_global_load_lds(
      (const __attribute__((address_space(1))) u32*)g,
      (__attribute__((address_space(3))) u32*)l, 16, 0, 0);
}

// half-swap: v_permlane32_swap_b32 A, B : A.hi-lanes <-> B.lo-lanes
static __device__ inline void swap32(u32 a, u32 b, u32& oa, u32& ob) {
#if __has_builtin(__builtin_amdgcn_permlane32_swap)
  auto r = __builtin_amdgcn_permlane32_swap(a, b, false, false);
  oa = r[0]; ob = r[1];
#else
  asm volatile("v_permlane32_swap_b32 %0, %1" : "+v"(a), "+v"(b));
  oa = a; ob = b;
#endif
}

// ---- prepass: Q -> scaled bf16 [bh][s][d]; K -> bf16 [bh][s][d];
//               V -> bf16 transposed [bh][d][s] ----
__global__ __launch_bounds__(256)
void prep_kernel(const float* __restrict__ Q, const float* __restrict__ K,
                 const float* __restrict__ V,
                 u16* __restrict__ Qb, u16* __restrict__ Kb, u16* __restrict__ VT) {
  __shared__ u16 tile[64 * kPadP];
  const int tid = threadIdx.x;
  const int bh = blockIdx.y, st = blockIdx.x;
  const size_t ibase = (size_t)bh * kS * kD + (size_t)st * 64 * kD;
  const int r  = tid >> 2;
  const int c0 = (tid & 3) * 16;
  {
    const float scl = 0.125f * 1.44269504089f;   // 1/sqrt(64) * log2(e)
    const float* qp = Q + ibase + (size_t)r * kD + c0;
    float4v a = *(const float4v*)(qp);
    float4v b = *(const float4v*)(qp + 4);
    float4v c = *(const float4v*)(qp + 8);
    float4v d = *(const float4v*)(qp + 12);
    #pragma unroll
    for (int i = 0; i < 4; ++i) { a[i] *= scl; b[i] *= scl; c[i] *= scl; d[i] *= scl; }
    u16* dst = Qb + ibase + (size_t)r * kD + c0;
    *(short8*)dst       = pack8(a, b);
    *(short8*)(dst + 8) = pack8(c, d);
  }
  {
    const float* kp = K + ibase + (size_t)r * kD + c0;
    float4v a = *(const float4v*)(kp);
    float4v b = *(const float4v*)(kp + 4);
    float4v c = *(const float4v*)(kp + 8);
    float4v d = *(const float4v*)(kp + 12);
    u16* dst = Kb + ibase + (size_t)r * kD + c0;
    *(short8*)dst       = pack8(a, b);
    *(short8*)(dst + 8) = pack8(c, d);
  }
  {
    const float* vp = V + ibase + (size_t)r * kD + c0;
    float4v a = *(const float4v*)(vp);
    float4v b = *(const float4v*)(vp + 4);
    float4v c = *(const float4v*)(vp + 8);
    float4v d = *(const float4v*)(vp + 12);
    u16* t = &tile[r * kPadP + c0];
    *(short8*)t       = pack8(a, b);
    *(short8*)(t + 8) = pack8(c, d);
  }
  __syncthreads();
  {
    const int dd = tid >> 2;
    const int s0 = (tid & 3) * 16;
    short8 w0, w1;
    #pragma unroll
    for (int i = 0; i < 8; ++i) {
      w0[i] = (short)tile[(s0 + i) * kPadP + dd];
      w1[i] = (short)tile[(s0 + 8 + i) * kPadP + dd];
    }
    u16* vdst = VT + (size_t)bh * kD * kS + (size_t)dd * kS + st * 64 + s0;
    *(short8*)vdst       = w0;
    *(short8*)(vdst + 8) = w1;
  }
}

// ---- main flash kernel: writes FINAL O ----
__global__ __launch_bounds__(256, 3)
void fattn_kernel(const u16* __restrict__ Qb, const u16* __restrict__ Kb,
                  const u16* __restrict__ VT, float* __restrict__ O) {
  // swizzled: 16B chunk c of row r stored at linear chunk r*8 + (c^(r&7))
  __shared__ __align__(16) u16 ldsK[2][4096];   // [buf][key 0..63][d]
  __shared__ __align__(16) u16 ldsV[2][4096];   // [buf][d 0..63][key]

  const int tid  = threadIdx.x;
  const int wave = tid >> 6;
  const int lane = tid & 63;
  const int l31  = lane & 31;
  const int h    = lane >> 5;
  const int g    = wave & 1;    // q-set: rows q0+32g .. q0+32g+31
  const int kpar = wave >> 1;   // key-parity: handles 32-key units with K32&1==kpar

  const int bh = blockIdx.y;
  const int qb = 31 - blockIdx.x;   // LPT: biggest blocks dispatched first
  const int q0 = qb * 64;

  const size_t base  = (size_t)bh * kS * kD;
  const size_t vbase = (size_t)bh * kD * kS;

  const int lr  = lane >> 3;
  const int cxl = (lane & 7) ^ lr;
  const int offK0 = lr * 64   + cxl * 8;
  const int offV0 = lr * 2048 + cxl * 8;
  const unsigned hs16 = ((unsigned)(h ^ (l31 & 7))) * 16;

  float16v zf;
  #pragma unroll
  for (int i = 0; i < 16; ++i) zf[i] = 0.f;

  // Q fragments (pre-scaled bf16) for own set only
  short8 qf[4];
  {
    const u16* qp = Qb + base + (size_t)(q0 + 32 * g + l31) * kD + h * 8;
    #pragma unroll
    for (int dk = 0; dk < 4; ++dk) qf[dk] = *(const short8*)(qp + dk * 16);
  }

  float16v acc0 = zf, acc1 = zf;
  float lac = 0.f;

  const int kmax = 2 * qb + g;   // max allowed 32-key unit index for this set

  // stage tile 0 into buf 0
  {
    const u16* kg0 = Kb + base;
    const u16* vg0 = VT + vbase;
    #pragma unroll
    for (int j = 0; j < 2; ++j) {
      const int gg = wave + 4 * j;
      async_cp16(kg0 + gg * 512 + offK0,           &ldsK[0][gg * 512]);
      async_cp16(vg0 + (size_t)gg * 16384 + offV0, &ldsV[0][gg * 512]);
    }
  }

  for (int t = 0; t <= qb; ++t) {
    __syncthreads();
    if (t < qb) {   // prefetch next tile
      const u16* kg0 = Kb + base + (size_t)(t + 1) * 4096;
      const u16* vg0 = VT + vbase + (t + 1) * 64;
      const int b = (t + 1) & 1;
      #pragma unroll
      for (int j = 0; j < 2; ++j) {
        const int gg = wave + 4 * j;
        async_cp16(kg0 + gg * 512 + offK0,           &ldsK[b][gg * 512]);
        async_cp16(vg0 + (size_t)gg * 16384 + offV0, &ldsV[b][gg * 512]);
      }
    }

    const int K32 = 2 * t + kpar;
    if (K32 <= kmax) {
      const char* KB = (const char*)ldsK[t & 1];
      const char* VB = (const char*)ldsV[t & 1];

      const char* krow = KB + (kpar * 32 + l31) * 128;
      short8 kf[4];
      #pragma unroll
      for (int dk = 0; dk < 4; ++dk)
        kf[dk] = *(const short8*)(krow + (((unsigned)(dk * 32)) ^ hs16));
      short8 vf[4];
      #pragma unroll
      for (int c = 0; c < 2; ++c) {
        const unsigned coff = ((unsigned)((kpar * 4 + 2 * c) * 16)) ^ hs16;
        vf[2 * c]     = *(const short8*)(VB + l31 * 128 + coff);
        vf[2 * c + 1] = *(const short8*)(VB + (32 + l31) * 128 + coff);
      }

      // S^T = K * Q^T (rows = keys, cols = q)
      __builtin_amdgcn_s_setprio(1);
      float16v s = __builtin_amdgcn_mfma_f32_32x32x16_bf16(kf[0], qf[0], zf, 0, 0, 0);
      s = __builtin_amdgcn_mfma_f32_32x32x16_bf16(kf[1], qf[1], s, 0, 0, 0);
      s = __builtin_amdgcn_mfma_f32_32x32x16_bf16(kf[2], qf[2], s, 0, 0, 0);
      s = __builtin_amdgcn_mfma_f32_32x32x16_bf16(kf[3], qf[3], s, 0, 0, 0);
      __builtin_amdgcn_s_setprio(0);

      if (K32 == kmax) {   // diagonal subtile of this set
        const int ktb = t * 64 + kpar * 32;
        const int qg  = q0 + 32 * g + l31;
        #pragma unroll
        for (int r = 0; r < 16; ++r) {
          const int kg = ktb + (r & 3) + 8 * (r >> 2) + 4 * h;
          if (kg > qg) s[r] = -1e30f;
        }
      }

      // p = exp2(s), pack (truncate) via v_perm
      u32 pk[8];
      #pragma unroll
      for (int g2 = 0; g2 < 4; ++g2) {
        const u32 u0 = __float_as_uint(__builtin_amdgcn_exp2f(s[4 * g2 + 0]));
        const u32 u1 = __float_as_uint(__builtin_amdgcn_exp2f(s[4 * g2 + 1]));
        const u32 u2 = __float_as_uint(__builtin_amdgcn_exp2f(s[4 * g2 + 2]));
        const u32 u3 = __float_as_uint(__builtin_amdgcn_exp2f(s[4 * g2 + 3]));
        pk[2 * g2]     = __builtin_amdgcn_perm(u1, u0, 0x07060302u);
        pk[2 * g2 + 1] = __builtin_amdgcn_perm(u3, u2, 0x07060302u);
      }

      // l partial: sum lane's 16 bf16-truncated P values (tree-shaped);
      // cross-lane/cross-wave halves deferred to epilogue.
      {
        float e[8];
        #pragma unroll
        for (int i = 0; i < 8; ++i)
          e[i] = __uint_as_float(pk[i] << 16)
               + __uint_as_float(pk[i] & 0xFFFF0000u);
        e[0] += e[1]; e[2] += e[3]; e[4] += e[5]; e[6] += e[7];
        e[0] += e[2]; e[4] += e[6];
        lac += e[0] + e[4];
      }

      // exchange partner half via permlane32_swap; PV MFMA
      #pragma unroll
      for (int c = 0; c < 2; ++c) {
        const int ga = 4 * c, gb = 4 * c + 2;
        union { u32 u[4]; short8 s8; } pf;
        swap32(pk[ga],     pk[gb],     pf.u[0], pf.u[2]);
        swap32(pk[ga + 1], pk[gb + 1], pf.u[1], pf.u[3]);
        __builtin_amdgcn_s_setprio(1);
        acc0 = __builtin_amdgcn_mfma_f32_32x32x16_bf16(pf.s8, vf[2 * c],     acc0, 0, 0, 0);
        acc1 = __builtin_amdgcn_mfma_f32_32x32x16_bf16(pf.s8, vf[2 * c + 1], acc1, 0, 0, 0);
        __builtin_amdgcn_s_setprio(0);
      }
    }
  }

  // ---- in-block combine across kpar waves; write FINAL fp32 O ----
  __syncthreads();   // all compute reads of LDS tiles done
  float* SA = (float*)&ldsK[0][0];   // 2 sets x 32 q x 64 d fp32 = 16 KB
  float* SL = (float*)&ldsV[0][0];   // 2 kpar x 2 sets x 32 q fp32

  const float lt = lac + __shfl_xor(lac, 32);   // both lane-halves hold l(q=l31)
  if (lane < 32) SL[kpar * 64 + g * 32 + lane] = lt;
  if (kpar == 1) {
    #pragma unroll
    for (int r = 0; r < 16; ++r) {
      const int row = (r & 3) + 8 * (r >> 2) + 4 * h;
      SA[(g * 32 + row) * 64 + l31]      = acc0[r];
      SA[(g * 32 + row) * 64 + 32 + l31] = acc1[r];
    }
  }
  __syncthreads();
  if (kpar == 0) {
    #pragma unroll
    for (int r = 0; r < 16; ++r) {
      const int row = (r & 3) + 8 * (r >> 2) + 4 * h;
      const float lsum = SL[g * 32 + row] + SL[64 + g * 32 + row];
      const float inv  = 1.f / lsum;
      const float o0 = (acc0[r] + SA[(g * 32 + row) * 64 + l31])      * inv;
      const float o1 = (acc1[r] + SA[(g * 32 + row) * 64 + 32 + l31]) * inv;
      float* op = O + ((size_t)bh * kS + q0 + 32 * g + row) * kD;
      op[l31]      = o0;
      op[l31 + 32] = o1;
    }
  }
}

extern "C" void kernel_launch(void* const* d_in, const int* in_sizes, int n_in,
                              void* d_out, int out_size, void* d_ws, size_t ws_size,
                              hipStream_t stream) {
  const float* Q = (const float*)d_in[0];
  const float* K = (const float*)d_in[1];
  const float* V = (const float*)d_in[2];
  float* O = (float*)d_out;

  const size_t nKV = (size_t)kBH * kS * kD;      // 4.19M elems
  u16* Qb = (u16*)d_ws;                          // 8.39 MB
  u16* Kb = Qb + nKV;                            // 8.39 MB
  u16* VT = Kb + nKV;                            // 8.39 MB

  dim3 gprep(kS / 64, kBH);
  prep_kernel<<<gprep, 256, 0, stream>>>(Q, K, V, Qb, Kb, VT);
  dim3 grid(kS / 64, kBH);   // x: 32 q-blocks (LPT-reversed), y: 32 bh
  fattn_kernel<<<grid, 256, 0, stream>>>(Qb, Kb, VT, O);
}